// Round 2
// baseline (855.533 us; speedup 1.0000x reference)
//
#include <hip/hip_runtime.h>

#define HH 256
#define WW 384
#define HWSZ (HH*WW)
#define NL 3
#define A2N 49
#define NBATCH 2
#define CN 3
#define RCN 12          // RANK*C
#define PADW (WW + 4)   // 2-halo each side

// Block = one image row (384 threads) for one (n, kidx); computes all 7 lidx
// views, all 12 rank-channels, 3 layers. Vertical lerp shared across lidx via
// LDS row with clamp-halo; horizontal lerp per lidx from ds_read2 pairs.
__global__ __launch_bounds__(WW) void multilayer_kernel(
    const float* __restrict__ low_rank,   // (N, L, RC, H, W)
    const float* __restrict__ planes,     // (N, L)
    float* __restrict__ out)              // (N, A2, C, H, W)
{
    __shared__ float vbuf[2 * PADW];      // double-buffered vlerp row

    // XCD-banded mapping: 3584 blocks = 8 xcd * (32 y-band * 14 nk)
    int b   = blockIdx.x;
    int xcd = b & 7;
    int i   = b >> 3;
    int y   = (xcd << 5) + (i & 31);      // each XCD owns a 32-row band
    int nk  = i >> 5;                     // 0..13
    int kq  = nk % 7;                     // kidx index 0..6
    int n   = nk / 7;
    float kf = (float)(kq - 3);

    int x = threadIdx.x;

    float acc[7][RCN];
#pragma unroll
    for (int j = 0; j < 7; j++)
#pragma unroll
        for (int rc = 0; rc < RCN; rc++) acc[j][rc] = 1.0f;

#pragma unroll
    for (int l = 0; l < NL; l++) {
        float p = planes[n * NL + l];

        // vertical params (uniform per block+layer)
        float dy  = p * (kf * (-0.5f * (float)(HH - 1) / (float)HH));
        float Yc  = fminf(fmaxf((float)y + dy, 0.0f), (float)(HH - 1));
        float y0f = floorf(Yc);
        int   y0  = (int)y0f;
        int   y1  = min(y0 + 1, HH - 1);
        float wy  = Yc - y0f;

        // horizontal params per lidx: ox = floor(dx) in {-2..1}, wx = frac
        // halo makes the unclamped (ox, wx) formula exact at borders
        float wxl[7];
        int   lofs[7];                    // LDS byte offset of vl[x+ox]
#pragma unroll
        for (int j = 0; j < 7; j++) {
            float dx  = p * ((float)(j - 3) * (-0.5f * (float)(WW - 1) / (float)WW));
            float oxf = floorf(dx);
            wxl[j]  = dx - oxf;
            lofs[j] = (x + (int)oxf + 2) << 2;
        }

        const float* b0 = low_rank + (size_t)n * (NL * RCN * HWSZ)
                          + (size_t)(l * RCN) * HWSZ + y0 * WW + x;
        const float* b1 = low_rank + (size_t)n * (NL * RCN * HWSZ)
                          + (size_t)(l * RCN) * HWSZ + y1 * WW + x;

        // software-pipelined over channels: next loads issue before barrier
        float g0 = b0[0];
        float g1 = b1[0];
#pragma unroll
        for (int rc = 0; rc < RCN; rc++) {
            int st   = l * RCN + rc;
            int boff = (st & 1) ? (int)(PADW * sizeof(float)) : 0;

            float v = fmaf(wy, g1 - g0, g0);

            float g0n = 0.f, g1n = 0.f;
            if (rc + 1 < RCN) {           // prefetch next channel
                g0n = b0[(rc + 1) * HWSZ];
                g1n = b1[(rc + 1) * HWSZ];
            }

            float* vb = (float*)((char*)vbuf + boff);
            vb[x + 2] = v;
            if (x == 0)      { vb[0] = v;      vb[1] = v; }
            if (x == WW - 1) { vb[WW + 2] = v; vb[WW + 3] = v; }
            __syncthreads();

#pragma unroll
            for (int j = 0; j < 7; j++) {
                const float* pa = (const float*)((char*)vbuf + boff + lofs[j]);
                float a0 = pa[0];
                float a1 = pa[1];
                float s  = fmaf(wxl[j], a1 - a0, a0);
                acc[j][rc] *= s;
            }

            g0 = g0n;
            g1 = g1n;
        }
    }

    // epilogue: mean over rank, write (n, a, c, y, x)
    size_t rowoff = (size_t)y * WW + x;
#pragma unroll
    for (int j = 0; j < 7; j++) {
        int a = kq * 7 + j;
        size_t ob = ((size_t)(n * A2N + a) * CN) * HWSZ + rowoff;
#pragma unroll
        for (int c = 0; c < CN; c++) {
            float s = acc[j][c] + acc[j][3 + c] + acc[j][6 + c] + acc[j][9 + c];
            out[ob + (size_t)c * HWSZ] = 0.25f * s;
        }
    }
}

extern "C" void kernel_launch(void* const* d_in, const int* in_sizes, int n_in,
                              void* d_out, int out_size, void* d_ws, size_t ws_size,
                              hipStream_t stream) {
    const float* low_rank = (const float*)d_in[0];
    const float* planes   = (const float*)d_in[1];
    float* out = (float*)d_out;

    int blocks = 8 * 32 * (NBATCH * 7);   // 3584: xcd-banded, 2*7*256 rows
    multilayer_kernel<<<blocks, WW, 0, stream>>>(low_rank, planes, out);
}